// Round 1
// baseline (438.158 us; speedup 1.0000x reference)
//
#include <hip/hip_runtime.h>

// GCN encoder: out = A' relu(A' (x W1) + b1) W2 + b2, A' = D^-1/2 (A+I) D^-1/2
// Trick: A'(h W) == (A' h) W  -> both propagations run on 16-dim features.

#define NN 100000
#define NE 1600000
#define FI 128
#define FH 16

__global__ void k_init_deg(float* __restrict__ deg, int n) {
    int i = blockIdx.x * blockDim.x + threadIdx.x;
    if (i < n) deg[i] = 1.0f;              // self-loop
}

__global__ void k_accum_deg(const int* __restrict__ dst, float* __restrict__ deg, int e) {
    int i = blockIdx.x * blockDim.x + threadIdx.x;
    if (i < e) atomicAdd(&deg[dst[i]], 1.0f);
}

__global__ void k_rsqrt(float* __restrict__ deg, int n) {
    int i = blockIdx.x * blockDim.x + threadIdx.x;
    if (i < n) deg[i] = rsqrtf(deg[i]);    // deg >= 1 always (self-loop)
}

// h1[n,16] = x[n,128] @ W1[128,16]; 16 nodes/block, 16 threads/node
__global__ __launch_bounds__(256) void k_gemm1(const float* __restrict__ x,
                                               const float* __restrict__ W1,
                                               float* __restrict__ h1, int n) {
    __shared__ float w[FI * FH];        // 2048 f32
    __shared__ float xs[16 * 132];      // 16 rows, stride 132 (132%32==4 -> no bank alias)
    for (int i = threadIdx.x; i < FI * FH; i += 256) w[i] = W1[i];
    int nodeBase = blockIdx.x * 16;
    for (int i = threadIdx.x; i < 16 * FI; i += 256) {   // coalesced global read
        int node = i >> 7, k = i & 127;
        int g = nodeBase + node;
        xs[node * 132 + k] = (g < n) ? x[g * FI + k] : 0.0f;
    }
    __syncthreads();
    int ln = threadIdx.x >> 4;          // local node 0..15
    int j  = threadIdx.x & 15;          // out feature
    float acc = 0.0f;
    #pragma unroll
    for (int k = 0; k < FI; ++k) acc += xs[ln * 132 + k] * w[k * FH + j];
    int g = nodeBase + ln;
    if (g < n) h1[g * FH + j] = acc;
}

// p[i,f] = h[i,f] * dinv[i]^2  (self-loop term; also zero-inits accumulator)
__global__ void k_selfloop(const float* __restrict__ h, const float* __restrict__ dinv,
                           float* __restrict__ p, int n16) {
    int i = blockIdx.x * blockDim.x + threadIdx.x;
    if (i < n16) {
        float d = dinv[i >> 4];
        p[i] = h[i] * d * d;
    }
}

// edge propagate: p[dst,f] += h[src,f]*dinv[src]*dinv[dst]; 16 lanes per edge
__global__ __launch_bounds__(256) void k_prop(const int* __restrict__ src,
                                              const int* __restrict__ dst,
                                              const float* __restrict__ h,
                                              const float* __restrict__ dinv,
                                              float* __restrict__ p, int e16) {
    int i = blockIdx.x * 256 + threadIdx.x;
    if (i >= e16) return;
    int eidx = i >> 4, f = i & 15;
    int s = src[eidx], d = dst[eidx];
    float norm = dinv[s] * dinv[d];
    atomicAdd(&p[d * FH + f], h[s * FH + f] * norm);
}

// h2 = relu(p1 + b1); p2 = h2 * dinv^2 (fused self-loop init for layer 2)
__global__ void k_relu_init(const float* __restrict__ p1, const float* __restrict__ b1,
                            const float* __restrict__ dinv,
                            float* __restrict__ h2, float* __restrict__ p2, int n16) {
    int i = blockIdx.x * blockDim.x + threadIdx.x;
    if (i < n16) {
        int node = i >> 4, f = i & 15;
        float v = p1[i] + b1[f];
        v = v > 0.0f ? v : 0.0f;
        float dd = dinv[node];
        h2[i] = v;
        p2[i] = v * dd * dd;
    }
}

// out[n,128] = p2[n,16] @ W2[16,128] + b2; 2 nodes/block, 128 threads/node
__global__ __launch_bounds__(256) void k_gemm2(const float* __restrict__ p2,
                                               const float* __restrict__ W2,
                                               const float* __restrict__ b2,
                                               float* __restrict__ out, int n) {
    __shared__ float w[FH * FI];   // 2048 f32
    __shared__ float ps[2 * FH];
    for (int i = threadIdx.x; i < FH * FI; i += 256) w[i] = W2[i];
    int nodeBase = blockIdx.x * 2;
    if (threadIdx.x < 32) {
        int node = threadIdx.x >> 4, k = threadIdx.x & 15;
        int g = nodeBase + node;
        ps[threadIdx.x] = (g < n) ? p2[g * FH + k] : 0.0f;
    }
    __syncthreads();
    int ln = threadIdx.x >> 7;     // local node 0..1
    int j  = threadIdx.x & 127;    // out feature
    float acc = b2[j];
    #pragma unroll
    for (int k = 0; k < FH; ++k) acc += ps[ln * FH + k] * w[k * FI + j];
    int g = nodeBase + ln;
    if (g < n) out[g * FI + j] = acc;
}

extern "C" void kernel_launch(void* const* d_in, const int* in_sizes, int n_in,
                              void* d_out, int out_size, void* d_ws, size_t ws_size,
                              hipStream_t stream) {
    const float* x  = (const float*)d_in[0];
    const int*   ei = (const int*)d_in[1];      // [2, NE] int32
    const float* W1 = (const float*)d_in[2];
    const float* b1 = (const float*)d_in[3];
    const float* W2 = (const float*)d_in[4];
    const float* b2 = (const float*)d_in[5];
    float* out = (float*)d_out;

    const int* src = ei;
    const int* dst = ei + NE;

    float* ws = (float*)d_ws;
    float* dinv = ws;                       // [NN]      (deg, then rsqrt in place)
    float* h1   = ws + 100352;              // [NN*16]   (reused as h2)
    float* p1   = h1 + NN * FH;             // [NN*16]
    float* p2   = p1 + NN * FH;             // [NN*16]

    const int n16 = NN * FH;                // 1.6M
    const int e16 = NE * FH;                // 25.6M

    k_init_deg <<<(NN + 255) / 256, 256, 0, stream>>>(dinv, NN);
    k_accum_deg<<<(NE + 255) / 256, 256, 0, stream>>>(dst, dinv, NE);
    k_rsqrt    <<<(NN + 255) / 256, 256, 0, stream>>>(dinv, NN);

    k_gemm1    <<<(NN + 15) / 16, 256, 0, stream>>>(x, W1, h1, NN);

    k_selfloop <<<(n16 + 255) / 256, 256, 0, stream>>>(h1, dinv, p1, n16);
    k_prop     <<<(e16 + 255) / 256, 256, 0, stream>>>(src, dst, h1, dinv, p1, e16);

    k_relu_init<<<(n16 + 255) / 256, 256, 0, stream>>>(p1, b1, dinv, h1, p2, n16);
    k_prop     <<<(e16 + 255) / 256, 256, 0, stream>>>(src, dst, h1, dinv, p2, e16);

    k_gemm2    <<<(NN + 1) / 2, 256, 0, stream>>>(p2, W2, b2, out, NN);
}